// Round 8
// baseline (122.206 us; speedup 1.0000x reference)
//
#include <hip/hip_runtime.h>

#define NPTS 65536

__device__ __forceinline__ float bf_lo(unsigned u) { return __uint_as_float(u << 16); }
__device__ __forceinline__ float bf_hi(unsigned u) { return __uint_as_float(u & 0xFFFF0000u); }
__device__ __forceinline__ unsigned short f2bf(float f) {      // RNE round
    unsigned u = __float_as_uint(f);
    return (unsigned short)((u + 0x7FFFu + ((u >> 16) & 1u)) >> 16);
}
__device__ __forceinline__ float bfu(unsigned short us) {
    return __uint_as_float(((unsigned)us) << 16);
}

// packed bf16 pair dot-accumulate: c + a.lo*b.lo + a.hi*b.hi
#if __has_builtin(__builtin_amdgcn_fdot2_f32_bf16)
typedef __bf16 bf16x2 __attribute__((ext_vector_type(2)));
__device__ __forceinline__ float dot2acc(unsigned a, unsigned b, float c) {
    return __builtin_amdgcn_fdot2_f32_bf16(__builtin_bit_cast(bf16x2, a),
                                           __builtin_bit_cast(bf16x2, b), c, false);
}
#else
__device__ __forceinline__ float dot2acc(unsigned a, unsigned b, float c) {
    return c + bf_lo(a) * bf_lo(b) + bf_hi(a) * bf_hi(b);
}
#endif

__device__ __forceinline__ float rdlane(float v, int lane) {
    return __uint_as_float((unsigned)__builtin_amdgcn_readlane((int)__float_as_uint(v), lane));
}

// ---------------- Kernel 1: M = WQ^T * WK for both attentions ----------------
__global__ __launch_bounds__(256) void k_matM(const float* __restrict__ WQa,
                                              const float* __restrict__ WKa,
                                              const float* __restrict__ WQe,
                                              const float* __restrict__ WKe,
                                              float* __restrict__ M) {
    __shared__ float WKs[4096];       // full WK, row-major [d][e]
    __shared__ float WQs[64][16];     // WQ columns c0..c0+15
    const int which = blockIdx.x >> 2;
    const int c0 = (blockIdx.x & 3) * 16;
    const float* WQ = which ? WQe : WQa;
    const float* WK = which ? WKe : WKa;
    const int t = threadIdx.x;
    #pragma unroll
    for (int i = 0; i < 16; ++i) WKs[t + i * 256] = WK[t + i * 256];
    #pragma unroll
    for (int i = 0; i < 4; ++i) {
        const int id = t + i * 256;
        WQs[id >> 4][id & 15] = WQ[(id >> 4) * 64 + c0 + (id & 15)];
    }
    __syncthreads();
    const int cc = t >> 4;
    const int eg = t & 15;
    float4 acc = make_float4(0.f, 0.f, 0.f, 0.f);
    #pragma unroll
    for (int d = 0; d < 64; ++d) {
        const float wq = WQs[d][cc];
        const float4 wk = *reinterpret_cast<const float4*>(&WKs[d * 64 + eg * 4]);
        acc.x += wq * wk.x; acc.y += wq * wk.y;
        acc.z += wq * wk.z; acc.w += wq * wk.w;
    }
    *reinterpret_cast<float4*>(&M[which * 4096 + (c0 + cc) * 64 + eg * 4]) = acc;
}

// ------- Kernel 2: fused pack (featT bf16) + qeff (bf16) ---------------------
__global__ __launch_bounds__(256) void k_prep(const float* __restrict__ spa,
                                              const float* __restrict__ spe,
                                              const float* __restrict__ M,
                                              unsigned short* __restrict__ featT,
                                              unsigned short* __restrict__ qeff) {
    __shared__ float tile[64][132];   // f32 staging, float4-aligned rows
    const int n0 = blockIdx.x * 64;
    const int t = threadIdx.x;
    {
        const int p = t & 63;
        const int c0 = t >> 6;
        #pragma unroll
        for (int i = 0; i < 32; ++i) {
            const int c = c0 + (i << 2);
            tile[p][c] = (c < 64) ? spa[c * NPTS + n0 + p]
                                  : spe[(c - 64) * NPTS + n0 + p];
        }
    }
    __syncthreads();
    const int c = t & 127;
    const int p0 = t >> 7;
    #pragma unroll
    for (int i = 0; i < 32; ++i) {    // bf16 pack-write (coalesced)
        const int p = p0 + (i << 1);
        featT[(size_t)(n0 + p) * 128 + c] = f2bf(tile[p][c]);
    }
    const int which = c >> 6;
    const int e = c & 63;
    float mcol[64];
    #pragma unroll
    for (int cc = 0; cc < 64; ++cc) mcol[cc] = M[which * 4096 + cc * 64 + e];
    for (int i = 0; i < 32; ++i) {
        const int p = p0 + (i << 1);
        const float4* fr = reinterpret_cast<const float4*>(&tile[p][which << 6]);
        float a0 = 0.f, a1 = 0.f, a2 = 0.f, a3 = 0.f;   // ILP-4
        #pragma unroll
        for (int c4 = 0; c4 < 16; c4 += 4) {
            const float4 v0 = fr[c4],     v1 = fr[c4 + 1];
            const float4 v2 = fr[c4 + 2], v3 = fr[c4 + 3];
            a0 += v0.x*mcol[4*c4]    + v0.y*mcol[4*c4+1]  + v0.z*mcol[4*c4+2]  + v0.w*mcol[4*c4+3];
            a1 += v1.x*mcol[4*c4+4]  + v1.y*mcol[4*c4+5]  + v1.z*mcol[4*c4+6]  + v1.w*mcol[4*c4+7];
            a2 += v2.x*mcol[4*c4+8]  + v2.y*mcol[4*c4+9]  + v2.z*mcol[4*c4+10] + v2.w*mcol[4*c4+11];
            a3 += v3.x*mcol[4*c4+12] + v3.y*mcol[4*c4+13] + v3.z*mcol[4*c4+14] + v3.w*mcol[4*c4+15];
        }
        qeff[(size_t)(n0 + p) * 128 + c] = f2bf((a0 + a1) + (a2 + a3));
    }
}

// ------ Kernel 3: FUSED attention + WV-projection + residual + write ---------
// Block = 4 waves x 8 points = 32 consecutive points.
// Score phase: lane = k*4+c4 (k-major, packed-bf16 dots, 12 shfl/point).
// PV phase: lane = channel; j[k], w[k] broadcast via readlane -> SGPR;
//           per-k coalesced ushort reloads (L1-hot) + FMA. No LDS, no fences.
// LDS: sctx [32][128] f32 (16384 B) overlaid by ctxT [128][35] (17920 B).
__global__ __launch_bounds__(256, 4) void k_fused(const unsigned short* __restrict__ featT,
                                                  const unsigned short* __restrict__ qeff,
                                                  const int* __restrict__ idx,
                                                  const float* __restrict__ spa,
                                                  const float* __restrict__ spe,
                                                  const float* __restrict__ WVa,
                                                  const float* __restrict__ bVa,
                                                  const float* __restrict__ WVe,
                                                  const float* __restrict__ bVe,
                                                  float* __restrict__ out) {
    __shared__ float smem[4480];           // 17920 B
    float* sctx = smem;                    // [32][128] (attention phase)
    float* ctxT = smem;                    // [128][35] (overlay, epilogue)
    const int t = threadIdx.x;
    const int wave = t >> 6;
    const int lane = t & 63;
    const int n0 = blockIdx.x * 32;
    const int k = lane >> 2;               // neighbor owned in score phase
    const int c4 = lane & 3;               // channel quarter (16 channels)

    for (int it = 0; it < 8; ++it) {
        const int pt = wave * 8 + it;      // block-local point
        const int n = n0 + pt;
        const int jv = idx[n * 16 + k];    // 4 lanes same addr -> broadcast
        const uint4* fx = reinterpret_cast<const uint4*>(featT + (size_t)jv * 128);
        const uint4 A0 = fx[2*c4],     A1 = fx[2*c4 + 1];      // spa 16 ch (packed)
        const uint4 E0 = fx[8 + 2*c4], E1 = fx[8 + 2*c4 + 1];  // spe 16 ch (packed)
        const uint4* qx = reinterpret_cast<const uint4*>(qeff + (size_t)n * 128);
        const uint4 QA0 = qx[2*c4],     QA1 = qx[2*c4 + 1];
        const uint4 QE0 = qx[8 + 2*c4], QE1 = qx[8 + 2*c4 + 1];

        // scores: spa att = q_spa . x_spe ; spe att = q_spe . x_spa
        float pa = 0.f, pe = 0.f;
        pa = dot2acc(QA0.x, E0.x, pa); pa = dot2acc(QA0.y, E0.y, pa);
        pa = dot2acc(QA0.z, E0.z, pa); pa = dot2acc(QA0.w, E0.w, pa);
        pa = dot2acc(QA1.x, E1.x, pa); pa = dot2acc(QA1.y, E1.y, pa);
        pa = dot2acc(QA1.z, E1.z, pa); pa = dot2acc(QA1.w, E1.w, pa);
        pe = dot2acc(QE0.x, A0.x, pe); pe = dot2acc(QE0.y, A0.y, pe);
        pe = dot2acc(QE0.z, A0.z, pe); pe = dot2acc(QE0.w, A0.w, pe);
        pe = dot2acc(QE1.x, A1.x, pe); pe = dot2acc(QE1.y, A1.y, pe);
        pe = dot2acc(QE1.z, A1.z, pe); pe = dot2acc(QE1.w, A1.w, pe);
        pa += __shfl_xor(pa, 1); pa += __shfl_xor(pa, 2);   // reduce over c4
        pe += __shfl_xor(pe, 1); pe += __shfl_xor(pe, 2);
        // |score| small by construction (0.02-scale weights) -> exp safe
        const float ea = __expf(pa * 0.125f);
        const float ee = __expf(pe * 0.125f);
        float da = ea, de = ee;
        #pragma unroll
        for (int m = 4; m < 64; m <<= 1) {  // sum over the 16 k, each once
            da += __shfl_xor(da, m);
            de += __shfl_xor(de, m);
        }
        const float wA = ea / da;           // per-lane: weight of its k
        const float wB = ee / de;

        // ---- PV: channel-major. lane owns channel c=lane of each half ----
        float accA = 0.f, accE = 0.f;
        #pragma unroll
        for (int kk = 0; kk < 16; ++kk) {
            const int jk = __builtin_amdgcn_readlane(jv, 4 * kk);   // -> SGPR
            const float wa = rdlane(wA, 4 * kk);
            const float wb = rdlane(wB, 4 * kk);
            const unsigned short* rp = featT + (size_t)jk * 128;
            accA += wa * bfu(rp[64 + lane]);   // ctx_spa from spe half
            accE += wb * bfu(rp[lane]);        // ctx_spe from spa half
        }
        sctx[pt * 128 + lane]      = accA;     // banks: 2-way, free
        sctx[pt * 128 + 64 + lane] = accE;
    }

    // ---------------- epilogue: ctx = WV*s + b, residual, write ----------
    const int d = t & 127;                 // output channel
    const int which = d >> 6;
    const int dd = d & 63;
    const int p0 = t >> 7;
    const float* WV = which ? WVe : WVa;
    float wrow[64];
    #pragma unroll
    for (int e4 = 0; e4 < 16; ++e4) {      // global loads, L2-hot
        const float4 w4 = *reinterpret_cast<const float4*>(WV + dd * 64 + e4 * 4);
        wrow[4*e4] = w4.x; wrow[4*e4+1] = w4.y; wrow[4*e4+2] = w4.z; wrow[4*e4+3] = w4.w;
    }
    const float bias = which ? bVe[dd] : bVa[dd];
    __syncthreads();                       // all sctx rows written
    float acc[16];
    #pragma unroll
    for (int i = 0; i < 16; ++i) {
        const int p = p0 + (i << 1);
        const float4* sr = reinterpret_cast<const float4*>(sctx + p * 128 + (which << 6));
        float a = bias;
        #pragma unroll
        for (int e4 = 0; e4 < 16; ++e4) {  // broadcast reads
            const float4 v = sr[e4];
            a += v.x * wrow[4*e4] + v.y * wrow[4*e4+1] + v.z * wrow[4*e4+2] + v.w * wrow[4*e4+3];
        }
        acc[i] = a;
    }
    __syncthreads();                       // sctx reads done -> ctxT overlay
    #pragma unroll
    for (int i = 0; i < 16; ++i) {
        ctxT[d * 35 + p0 + (i << 1)] = acc[i];   // (3d+p)%32 -> 2-way, free
    }
    __syncthreads();
    {
        const int p = t & 31;
        const int ch0 = t >> 5;
        #pragma unroll
        for (int i = 0; i < 16; ++i) {
            const int ch = ch0 + (i << 3);
            const float f = (ch < 64) ? spa[ch * NPTS + n0 + p]
                                      : spe[(ch - 64) * NPTS + n0 + p];
            out[(size_t)ch * NPTS + n0 + p] = f + ctxT[ch * 35 + p];
        }
    }
}

extern "C" void kernel_launch(void* const* d_in, const int* in_sizes, int n_in,
                              void* d_out, int out_size, void* d_ws, size_t ws_size,
                              hipStream_t stream) {
    const float* spa = (const float*)d_in[0];
    const float* spe = (const float*)d_in[1];
    const int* idx   = (const int*)d_in[2];
    const float* WQa = (const float*)d_in[3];
    const float* WKa = (const float*)d_in[4];
    const float* WVa = (const float*)d_in[5];
    const float* bVa = (const float*)d_in[6];
    const float* WQe = (const float*)d_in[7];
    const float* WKe = (const float*)d_in[8];
    const float* WVe = (const float*)d_in[9];
    const float* bVe = (const float*)d_in[10];
    float* out = (float*)d_out;

    char* ws = (char*)d_ws;
    unsigned short* featT = (unsigned short*)(ws);              // 16.78 MB bf16 [N][128]
    unsigned short* qeff  = (unsigned short*)(ws + 16777216);   // 16.78 MB bf16 [N][128]
    float* Mmat = (float*)(ws + 33554432);                      // 32 KB f32 [2][64][64]

    k_matM<<<8, 256, 0, stream>>>(WQa, WKa, WQe, WKe, Mmat);
    k_prep<<<1024, 256, 0, stream>>>(spa, spe, Mmat, featT, qeff);
    k_fused<<<2048, 256, 0, stream>>>(featT, qeff, idx, spa, spe,
                                      WVa, bVa, WVe, bVe, out);
}